// Round 3
// baseline (35574.506 us; speedup 1.0000x reference)
//
#include <hip/hip_runtime.h>
#include <cmath>

#define CH   256
#define IMH  120
#define IMW  200
#define HWN  24000        // 120*200
#define NBATCH 4
#define PPB  188          // ceil(24000/128) pixel tiles per batch
#define PNUM 200

// workspace layout (float offsets). Total = 75,261,184 floats = ~301 MB.
#define X0_OFF   0
#define H1_OFF   24576000
#define XX_OFF   49152000
#define DEP_OFF  73728000
#define OFM_OFF  73824000
#define A0_OFF   74016000
#define A1_OFF   74081536
#define A2_OFF   74671360

// ---------------------------------------------------------------------------
// Weight reorder: src [oc][ic][taps] -> dst [tap][ic][oc]
// ---------------------------------------------------------------------------
__global__ void reorder_w_kernel(const float* __restrict__ src,
                                 float* __restrict__ dst, int taps) {
    int e = blockIdx.x * 256 + threadIdx.x;
    int total = CH * CH * taps;
    if (e >= total) return;
    int oc  = e / (CH * taps);
    int rem = e - oc * (CH * taps);
    int ic  = rem / taps;
    int t   = rem - ic * taps;
    dst[(t * CH + ic) * CH + oc] = src[e];
}

// ---------------------------------------------------------------------------
// Implicit-GEMM conv.  out[oc][px] = sum_{t,ic} A[t][ic][oc] * in[ic][h+dy][w+dx]
// MODE 0: out = acc + p0[oc]                      (conv1x1 + bias)
// MODE 1: out = relu(acc*p0[oc] + p1[oc])         (conv3x3 + BN + relu)
// MODE 2: out = relu(acc*p0[oc] + p1[oc] + resid) (conv3x3 + BN + residual + relu)
// Tile: 128 oc x 128 px, BK=8, 256 threads, 8x8 micro-tile, double-buffered
// LDS (16 KB), one barrier per K-step, loads issued before compute (T14).
// ---------------------------------------------------------------------------
template <int TAPS, int MODE>
__global__ __launch_bounds__(256, 4)
void conv_gemm_kernel(const float* __restrict__ in, const float* __restrict__ Aw,
                      const float* __restrict__ p0, const float* __restrict__ p1,
                      const float* __restrict__ resid, float* __restrict__ out) {
    const int tid = threadIdx.x;
    const int b   = blockIdx.x / PPB;
    const int hw0 = (blockIdx.x % PPB) * 128;
    const int oc0 = blockIdx.y * 128;
    const int ti  = tid >> 4;      // 0..15 -> oc group of 8
    const int tj  = tid & 15;      // 0..15 -> px group of 4 (+64)

    __shared__ float As[2][8][128];
    __shared__ float Bs[2][8][128];

    float acc[8][8];
#pragma unroll
    for (int i = 0; i < 8; ++i)
#pragma unroll
        for (int j = 0; j < 8; ++j) acc[i][j] = 0.f;

    // staging assignment: thread stages one float4 of A and 4 elems of B
    const int sk = tid >> 5;         // 0..7 (k row)
    const int sc = (tid & 31) * 4;   // col (oc or px), multiple of 4

    // B pixel geometry for the 4 staged elements (computed once)
    int ph[4], pw[4];
    bool pv[4];
    {
        const int px0 = hw0 + sc;
        int phh = px0 / IMW;
        int pww = px0 - phh * IMW;
#pragma unroll
        for (int e = 0; e < 4; ++e) {
            ph[e] = phh; pw[e] = pww;
            pv[e] = (px0 + e) < HWN;
            if (++pww == IMW) { pww = 0; ++phh; }
        }
    }

    const float* inb = in + (size_t)b * (CH * HWN);
    const int NS = TAPS * 32;     // K-steps of 8

    float4 aA;
    float  vB[4];
    bool   okB[4];

#define ISSUE(sNext)                                                        \
    {                                                                       \
        const int tap_ = (TAPS == 9) ? ((sNext) >> 5) : 0;                  \
        const int kc_  = (sNext) & 31;                                      \
        const int ic_  = kc_ * 8 + sk;                                      \
        const int dy_  = (TAPS == 9) ? (tap_ / 3 - 1) : 0;                  \
        const int dx_  = (TAPS == 9) ? (tap_ - (tap_ / 3) * 3 - 1) : 0;     \
        aA = *(const float4*)(Aw + ((tap_ * CH + ic_) * CH + oc0 + sc));    \
        _Pragma("unroll")                                                   \
        for (int e = 0; e < 4; ++e) {                                       \
            const int hh_ = ph[e] + dy_, ww_ = pw[e] + dx_;                 \
            okB[e] = pv[e] && ((unsigned)hh_ < IMH) && ((unsigned)ww_ < IMW);\
            const int off_ = okB[e] ? (ic_ * HWN + hh_ * IMW + ww_) : 0;    \
            vB[e] = inb[off_];                                              \
        }                                                                   \
    }

#define COMMIT(buf)                                                         \
    {                                                                       \
        float4 bv;                                                          \
        bv.x = okB[0] ? vB[0] : 0.f;                                        \
        bv.y = okB[1] ? vB[1] : 0.f;                                        \
        bv.z = okB[2] ? vB[2] : 0.f;                                        \
        bv.w = okB[3] ? vB[3] : 0.f;                                        \
        *(float4*)(&As[buf][sk][sc]) = aA;                                  \
        *(float4*)(&Bs[buf][sk][sc]) = bv;                                  \
    }

    // prologue: stage tile 0 into buffer 0
    ISSUE(0);
    COMMIT(0);
    __syncthreads();

    int cur = 0;
#pragma unroll 1
    for (int s = 0; s < NS; ++s) {
        if (s + 1 < NS) ISSUE(s + 1);

#pragma unroll
        for (int k = 0; k < 8; ++k) {
            const float4 a0 = *(const float4*)(&As[cur][k][ti * 8]);
            const float4 a1 = *(const float4*)(&As[cur][k][ti * 8 + 4]);
            const float4 b0 = *(const float4*)(&Bs[cur][k][tj * 4]);
            const float4 b1 = *(const float4*)(&Bs[cur][k][64 + tj * 4]);
            const float av[8] = {a0.x, a0.y, a0.z, a0.w, a1.x, a1.y, a1.z, a1.w};
            const float bv[8] = {b0.x, b0.y, b0.z, b0.w, b1.x, b1.y, b1.z, b1.w};
#pragma unroll
            for (int i = 0; i < 8; ++i)
#pragma unroll
                for (int j = 0; j < 8; ++j)
                    acc[i][j] = fmaf(av[i], bv[j], acc[i][j]);
        }

        if (s + 1 < NS) COMMIT(cur ^ 1);
        __syncthreads();
        cur ^= 1;
    }
#undef ISSUE
#undef COMMIT

    // epilogue
    const int ocb = oc0 + ti * 8;
#pragma unroll
    for (int i = 0; i < 8; ++i) {
        const int oc = ocb + i;
        float sS, bi;
        if constexpr (MODE == 0) { sS = 1.f; bi = p0[oc]; }
        else                     { sS = p0[oc]; bi = p1[oc]; }
        float* op = out + ((size_t)b * CH + oc) * HWN;
        const float* rp = (MODE == 2) ? (resid + ((size_t)b * CH + oc) * HWN) : nullptr;
#pragma unroll
        for (int g = 0; g < 2; ++g) {
            const int hw = hw0 + g * 64 + tj * 4;
            if (hw < HWN) {
                float v0 = acc[i][g * 4 + 0] * sS + bi;
                float v1 = acc[i][g * 4 + 1] * sS + bi;
                float v2 = acc[i][g * 4 + 2] * sS + bi;
                float v3 = acc[i][g * 4 + 3] * sS + bi;
                if constexpr (MODE == 2) {
                    const float4 r = *(const float4*)(&rp[hw]);
                    v0 += r.x; v1 += r.y; v2 += r.z; v3 += r.w;
                }
                if constexpr (MODE != 0) {
                    v0 = fmaxf(v0, 0.f); v1 = fmaxf(v1, 0.f);
                    v2 = fmaxf(v2, 0.f); v3 = fmaxf(v3, 0.f);
                }
                *(float4*)(&op[hw]) = make_float4(v0, v1, v2, v3);
            }
        }
    }
}

// ---------------------------------------------------------------------------
// Heads: per-pixel 256-wide dots for obj / depth / offset(2).
// ---------------------------------------------------------------------------
__global__ __launch_bounds__(256)
void heads_kernel(const float* __restrict__ x,
                  const float* __restrict__ w_obj, const float* __restrict__ b_obj,
                  const float* __restrict__ w_dep, const float* __restrict__ b_dep,
                  const float* __restrict__ w_off, const float* __restrict__ b_off,
                  float* __restrict__ obj_out, float* __restrict__ depth_out,
                  float* __restrict__ off_out) {
    __shared__ float wo[256], wd[256], w0[256], w1[256];
    const int tid = threadIdx.x;
    wo[tid] = w_obj[tid];
    wd[tid] = w_dep[tid];
    w0[tid] = w_off[tid];
    w1[tid] = w_off[256 + tid];
    __syncthreads();

    const int g  = blockIdx.x * 256 + tid;   // 0..95999
    const int b  = g / HWN;
    const int hw = g - b * HWN;
    const float* xp = x + ((size_t)b * CH) * HWN + hw;

    float ao = 0.f, ad = 0.f, a0 = 0.f, a1 = 0.f;
#pragma unroll 8
    for (int c = 0; c < CH; ++c) {
        const float v = xp[(size_t)c * HWN];
        ao = fmaf(wo[c], v, ao);
        ad = fmaf(wd[c], v, ad);
        a0 = fmaf(w0[c], v, a0);
        a1 = fmaf(w1[c], v, a1);
    }
    const float zo = ao + b_obj[0];
    float so = 1.f / (1.f + expf(-zo));
    so = fminf(fmaxf(so, 1e-4f), 1.f - 1e-4f);
    obj_out[g] = so;

    const float zd = ad + b_dep[0];
    const float sd = 1.f / (1.f + expf(-zd));
    depth_out[g] = 1.f / sd - 1.f;

    off_out[(b * 2 + 0) * HWN + hw] = a0 + b_off[0];
    off_out[(b * 2 + 1) * HWN + hw] = a1 + b_off[1];
}

// ---------------------------------------------------------------------------
// Top-200 (exact, jax.lax.top_k tie semantics: value desc, index asc) via
// 3-pass radix select on float bits, then bitonic sort of candidates, then
// fused grid-sample + K^-1 projection epilogue.  One block per batch.
// ---------------------------------------------------------------------------
__global__ __launch_bounds__(256)
void topk_final_kernel(const float* __restrict__ obj,
                       const float* __restrict__ depth_map,
                       const float* __restrict__ off_map,
                       const float* __restrict__ Ks,
                       float* __restrict__ conf_out,
                       float* __restrict__ xyz_out) {
    const int b   = blockIdx.x;
    const int tid = threadIdx.x;
    const float* data = obj + b * HWN;

    __shared__ unsigned hist[2048];
    __shared__ unsigned partial[256];
    __shared__ unsigned sh_sel, sh_cum;
    __shared__ unsigned long long comp[1024];
    __shared__ unsigned ncand;

    unsigned prefix = 0;
    int r = PNUM;

    for (int lvl = 0; lvl < 3; ++lvl) {
        const int shift  = (lvl == 0) ? 21 : (lvl == 1) ? 10 : 0;
        const int bits   = (lvl == 2) ? 10 : 11;
        const int nb     = 1 << bits;
        const int pshift = shift + bits;

        for (int i = tid; i < 2048; i += 256) hist[i] = 0;
        __syncthreads();
        for (int i = tid; i < HWN; i += 256) {
            const unsigned k = __float_as_uint(data[i]);
            if (lvl == 0 || (k >> pshift) == prefix)
                atomicAdd(&hist[(k >> shift) & (nb - 1)], 1u);
        }
        __syncthreads();
        const int per = nb / 256;
        unsigned ps = 0;
        for (int j = 0; j < per; ++j) ps += hist[tid * per + j];
        partial[tid] = ps;
        __syncthreads();
        if (tid == 0) {
            unsigned cum = 0;
            int chunk = 0;
            for (int c = 255; c >= 0; --c) {
                if (cum + partial[c] >= (unsigned)r) { chunk = c; break; }
                cum += partial[c];
            }
            int selb = 0;
            for (int c2 = chunk * per + per - 1;; --c2) {
                if (cum + hist[c2] >= (unsigned)r) { selb = c2; break; }
                cum += hist[c2];
            }
            sh_sel = (unsigned)selb;
            sh_cum = cum;
        }
        __syncthreads();
        prefix = (prefix << bits) | sh_sel;
        r -= (int)sh_cum;
        __syncthreads();
    }
    const unsigned T = prefix;    // exact 200th-largest key

    if (tid == 0) ncand = 0;
    __syncthreads();
    for (int i = tid; i < HWN; i += 256) {
        const unsigned k = __float_as_uint(data[i]);
        if (k >= T) {
            const unsigned pos = atomicAdd(&ncand, 1u);
            if (pos < 1024)
                comp[pos] = ((unsigned long long)k << 32) | (unsigned)(~(unsigned)i);
        }
    }
    __syncthreads();
    const unsigned n = (ncand > 1024u) ? 1024u : ncand;
    for (int i = tid; i < 1024; i += 256)
        if ((unsigned)i >= n) comp[i] = 0ULL;
    __syncthreads();

    // bitonic sort, descending (key desc; ~idx desc == idx asc)
    for (int ksz = 2; ksz <= 1024; ksz <<= 1) {
        for (int jj = ksz >> 1; jj > 0; jj >>= 1) {
            __syncthreads();
            for (int e = tid; e < 1024; e += 256) {
                const int l = e ^ jj;
                if (l > e) {
                    const unsigned long long a = comp[e], c = comp[l];
                    const bool sw = ((e & ksz) == 0) ? (a < c) : (a > c);
                    if (sw) { comp[e] = c; comp[l] = a; }
                }
            }
        }
    }
    __syncthreads();

    if (tid < PNUM) {
        const unsigned long long c = comp[tid];
        const float conf = __uint_as_float((unsigned)(c >> 32));
        const int idx = (int)(~(unsigned)(c & 0xffffffffu));

        const float fu = (float)(idx % IMW);
        const float fv = (float)(idx / IMH);       // faithful: // feat_h (=120)
        const float nu = (fu - 100.f) / 100.f;
        const float nv = (fv - fv / 2.0f) / 60.f;  // faithful source expression

        const float xx = ((nu + 1.f) * 200.f - 1.f) * 0.5f;
        const float yy = ((nv + 1.f) * 120.f - 1.f) * 0.5f;
        const float x0f = floorf(xx), y0f = floorf(yy);
        const float wx1 = xx - x0f, wx0 = 1.f - wx1;
        const float wy1 = yy - y0f, wy0 = 1.f - wy1;

        const float* dm  = depth_map + b * HWN;
        const float* om0 = off_map + (b * 2) * HWN;
        const float* om1 = om0 + HWN;

        float d = 0.f, o0 = 0.f, o1 = 0.f;
#pragma unroll
        for (int cy = 0; cy < 2; ++cy) {
#pragma unroll
            for (int cx = 0; cx < 2; ++cx) {
                const float ix = x0f + (float)cx;
                const float iy = y0f + (float)cy;
                const float wgt = (cx ? wx1 : wx0) * (cy ? wy1 : wy0);
                const bool val = (ix >= 0.f) && (ix < 200.f) &&
                                 (iy >= 0.f) && (iy < 120.f);
                if (val) {
                    const int ixi = (int)ix;
                    const int iyi = (int)iy;
                    const int off = iyi * IMW + ixi;
                    d  = fmaf(dm[off],  wgt, d);
                    o0 = fmaf(om0[off], wgt, o0);
                    o1 = fmaf(om1[off], wgt, o1);
                }
            }
        }

        const float cu = (fu + o0) * 16.f;
        const float cv = (fv + o1) * 16.f;
        const float X = cu * d, Y = cv * d, Z = d;

        const float* K = Ks + b * 9;
        const float k0 = K[0], k1 = K[1], k2 = K[2];
        const float k3 = K[3], k4 = K[4], k5 = K[5];
        const float k6 = K[6], k7 = K[7], k8 = K[8];
        const float det = k0 * (k4 * k8 - k5 * k7)
                        - k1 * (k3 * k8 - k5 * k6)
                        + k2 * (k3 * k7 - k4 * k6);
        const float id_ = 1.f / det;
        const float i00 = (k4 * k8 - k5 * k7) * id_;
        const float i01 = (k2 * k7 - k1 * k8) * id_;
        const float i02 = (k1 * k5 - k2 * k4) * id_;
        const float i10 = (k5 * k6 - k3 * k8) * id_;
        const float i11 = (k0 * k8 - k2 * k6) * id_;
        const float i12 = (k2 * k3 - k0 * k5) * id_;
        const float i20 = (k3 * k7 - k4 * k6) * id_;
        const float i21 = (k1 * k6 - k0 * k7) * id_;
        const float i22 = (k0 * k4 - k1 * k3) * id_;

        conf_out[b * PNUM + tid] = conf;
        float* xp = xyz_out + (b * PNUM + tid) * 3;
        xp[0] = i00 * X + i01 * Y + i02 * Z;
        xp[1] = i10 * X + i11 * Y + i12 * Z;
        xp[2] = i20 * X + i21 * Y + i22 * Z;
    }
}

// ---------------------------------------------------------------------------
extern "C" void kernel_launch(void* const* d_in, const int* in_sizes, int n_in,
                              void* d_out, int out_size, void* d_ws, size_t ws_size,
                              hipStream_t stream) {
    const float* feat  = (const float*)d_in[0];
    const float* Ks    = (const float*)d_in[1];
    const float* w_sc  = (const float*)d_in[2];
    const float* b_sc  = (const float*)d_in[3];
    const float* w_bb1 = (const float*)d_in[4];
    const float* bn1s  = (const float*)d_in[5];
    const float* bn1b  = (const float*)d_in[6];
    const float* w_bb2 = (const float*)d_in[7];
    const float* bn2s  = (const float*)d_in[8];
    const float* bn2b  = (const float*)d_in[9];
    const float* w_obj = (const float*)d_in[10];
    const float* b_obj = (const float*)d_in[11];
    const float* w_dep = (const float*)d_in[12];
    const float* b_dep = (const float*)d_in[13];
    const float* w_off = (const float*)d_in[14];
    const float* b_off = (const float*)d_in[15];

    float* out = (float*)d_out;
    float* ws  = (float*)d_ws;

    float* x0    = ws + X0_OFF;
    float* h1    = ws + H1_OFF;
    float* xx    = ws + XX_OFF;
    float* depth = ws + DEP_OFF;
    float* offm  = ws + OFM_OFF;
    float* A0    = ws + A0_OFF;
    float* A1    = ws + A1_OFF;
    float* A2    = ws + A2_OFF;

    reorder_w_kernel<<<256, 256, 0, stream>>>(w_sc, A0, 1);
    reorder_w_kernel<<<2304, 256, 0, stream>>>(w_bb1, A1, 9);
    reorder_w_kernel<<<2304, 256, 0, stream>>>(w_bb2, A2, 9);

    dim3 cgrid(PPB * NBATCH, 2);
    conv_gemm_kernel<1, 0><<<cgrid, 256, 0, stream>>>(feat, A0, b_sc, nullptr, nullptr, x0);
    conv_gemm_kernel<9, 1><<<cgrid, 256, 0, stream>>>(x0, A1, bn1s, bn1b, nullptr, h1);
    conv_gemm_kernel<9, 2><<<cgrid, 256, 0, stream>>>(h1, A2, bn2s, bn2b, x0, xx);

    heads_kernel<<<375, 256, 0, stream>>>(xx, w_obj, b_obj, w_dep, b_dep,
                                          w_off, b_off, out, depth, offm);

    topk_final_kernel<<<NBATCH, 256, 0, stream>>>(out, depth, offm, Ks,
                                                  out + NBATCH * HWN,
                                                  out + NBATCH * HWN + NBATCH * PNUM);
}

// Round 4
// 14937.633 us; speedup vs baseline: 2.3815x; 2.3815x over previous
//
#include <hip/hip_runtime.h>
#include <cmath>

#define CH   256
#define IMH  120
#define IMW  200
#define HWN  24000        // 120*200
#define NBATCH 4
#define PPB  188          // ceil(24000/128) pixel tiles per batch
#define PNUM 200

// workspace layout (float offsets). Total = 75,261,184 floats = ~301 MB.
#define X0_OFF   0
#define H1_OFF   24576000
#define XX_OFF   49152000
#define DEP_OFF  73728000
#define OFM_OFF  73824000
#define A0_OFF   74016000
#define A1_OFF   74081536
#define A2_OFF   74671360

// ---------------------------------------------------------------------------
// Weight reorder: src [oc][ic][taps] -> dst [tap][ic][oc]
// ---------------------------------------------------------------------------
__global__ void reorder_w_kernel(const float* __restrict__ src,
                                 float* __restrict__ dst, int taps) {
    int e = blockIdx.x * 256 + threadIdx.x;
    int total = CH * CH * taps;
    if (e >= total) return;
    int oc  = e / (CH * taps);
    int rem = e - oc * (CH * taps);
    int ic  = rem / taps;
    int t   = rem - ic * taps;
    dst[(t * CH + ic) * CH + oc] = src[e];
}

// ---------------------------------------------------------------------------
// Implicit-GEMM conv.  out[oc][px] = sum_{t,ic} A[t][ic][oc] * in[ic][h+dy][w+dx]
// MODE 0: out = acc + p0[oc]                      (conv1x1 + bias)
// MODE 1: out = relu(acc*p0[oc] + p1[oc])         (conv3x3 + BN + relu)
// MODE 2: out = relu(acc*p0[oc] + p1[oc] + resid) (conv3x3 + BN + residual + relu)
// Tile: 128 oc x 128 px, BK=8, 256 threads, 8x8 micro-tile, double-buffered
// LDS (16 KB), one barrier per K-step, loads issued before compute (T14).
// __launch_bounds__(256,3): 3 waves/SIMD -> ~170 VGPR cap. (256,4) capped at
// 128 and SPILLED the 8x8 accumulator (55 GB scratch writes/dispatch, R3).
// 3 blocks/CU x 256 CU = 768 >= 752-block grid: fully co-resident, no tail.
// ---------------------------------------------------------------------------
template <int TAPS, int MODE>
__global__ __launch_bounds__(256, 3)
void conv_gemm_kernel(const float* __restrict__ in, const float* __restrict__ Aw,
                      const float* __restrict__ p0, const float* __restrict__ p1,
                      const float* __restrict__ resid, float* __restrict__ out) {
    const int tid = threadIdx.x;
    const int b   = blockIdx.x / PPB;
    const int hw0 = (blockIdx.x % PPB) * 128;
    const int oc0 = blockIdx.y * 128;
    const int ti  = tid >> 4;      // 0..15 -> oc group of 8
    const int tj  = tid & 15;      // 0..15 -> px group of 4 (+64)

    __shared__ float As[2][8][128];
    __shared__ float Bs[2][8][128];

    float acc[8][8];
#pragma unroll
    for (int i = 0; i < 8; ++i)
#pragma unroll
        for (int j = 0; j < 8; ++j) acc[i][j] = 0.f;

    // staging assignment: thread stages one float4 of A and 4 elems of B
    const int sk = tid >> 5;         // 0..7 (k row)
    const int sc = (tid & 31) * 4;   // col (oc or px), multiple of 4

    // B pixel geometry for the 4 staged elements (computed once)
    int ph[4], pw[4];
    bool pv[4];
    {
        const int px0 = hw0 + sc;
        int phh = px0 / IMW;
        int pww = px0 - phh * IMW;
#pragma unroll
        for (int e = 0; e < 4; ++e) {
            ph[e] = phh; pw[e] = pww;
            pv[e] = (px0 + e) < HWN;
            if (++pww == IMW) { pww = 0; ++phh; }
        }
    }

    const float* inb = in + (size_t)b * (CH * HWN);
    const int NS = TAPS * 32;     // K-steps of 8

    float4 aA;
    float  vB[4];
    bool   okB[4];

#define ISSUE(sNext)                                                        \
    {                                                                       \
        const int tap_ = (TAPS == 9) ? ((sNext) >> 5) : 0;                  \
        const int kc_  = (sNext) & 31;                                      \
        const int ic_  = kc_ * 8 + sk;                                      \
        const int dy_  = (TAPS == 9) ? (tap_ / 3 - 1) : 0;                  \
        const int dx_  = (TAPS == 9) ? (tap_ - (tap_ / 3) * 3 - 1) : 0;     \
        aA = *(const float4*)(Aw + ((tap_ * CH + ic_) * CH + oc0 + sc));    \
        _Pragma("unroll")                                                   \
        for (int e = 0; e < 4; ++e) {                                       \
            const int hh_ = ph[e] + dy_, ww_ = pw[e] + dx_;                 \
            okB[e] = pv[e] && ((unsigned)hh_ < IMH) && ((unsigned)ww_ < IMW);\
            const int off_ = okB[e] ? (ic_ * HWN + hh_ * IMW + ww_) : 0;    \
            vB[e] = inb[off_];                                              \
        }                                                                   \
    }

#define COMMIT(buf)                                                         \
    {                                                                       \
        float4 bv;                                                          \
        bv.x = okB[0] ? vB[0] : 0.f;                                        \
        bv.y = okB[1] ? vB[1] : 0.f;                                        \
        bv.z = okB[2] ? vB[2] : 0.f;                                        \
        bv.w = okB[3] ? vB[3] : 0.f;                                        \
        *(float4*)(&As[buf][sk][sc]) = aA;                                  \
        *(float4*)(&Bs[buf][sk][sc]) = bv;                                  \
    }

    // prologue: stage tile 0 into buffer 0
    ISSUE(0);
    COMMIT(0);
    __syncthreads();

    int cur = 0;
#pragma unroll 1
    for (int s = 0; s < NS; ++s) {
        if (s + 1 < NS) ISSUE(s + 1);

#pragma unroll
        for (int k = 0; k < 8; ++k) {
            const float4 a0 = *(const float4*)(&As[cur][k][ti * 8]);
            const float4 a1 = *(const float4*)(&As[cur][k][ti * 8 + 4]);
            const float4 b0 = *(const float4*)(&Bs[cur][k][tj * 4]);
            const float4 b1 = *(const float4*)(&Bs[cur][k][64 + tj * 4]);
            const float av[8] = {a0.x, a0.y, a0.z, a0.w, a1.x, a1.y, a1.z, a1.w};
            const float bv[8] = {b0.x, b0.y, b0.z, b0.w, b1.x, b1.y, b1.z, b1.w};
#pragma unroll
            for (int i = 0; i < 8; ++i)
#pragma unroll
                for (int j = 0; j < 8; ++j)
                    acc[i][j] = fmaf(av[i], bv[j], acc[i][j]);
        }

        if (s + 1 < NS) COMMIT(cur ^ 1);
        __syncthreads();
        cur ^= 1;
    }
#undef ISSUE
#undef COMMIT

    // epilogue
    const int ocb = oc0 + ti * 8;
#pragma unroll
    for (int i = 0; i < 8; ++i) {
        const int oc = ocb + i;
        float sS, bi;
        if constexpr (MODE == 0) { sS = 1.f; bi = p0[oc]; }
        else                     { sS = p0[oc]; bi = p1[oc]; }
        float* op = out + ((size_t)b * CH + oc) * HWN;
        const float* rp = (MODE == 2) ? (resid + ((size_t)b * CH + oc) * HWN) : nullptr;
#pragma unroll
        for (int g = 0; g < 2; ++g) {
            const int hw = hw0 + g * 64 + tj * 4;
            if (hw < HWN) {
                float v0 = acc[i][g * 4 + 0] * sS + bi;
                float v1 = acc[i][g * 4 + 1] * sS + bi;
                float v2 = acc[i][g * 4 + 2] * sS + bi;
                float v3 = acc[i][g * 4 + 3] * sS + bi;
                if constexpr (MODE == 2) {
                    const float4 r = *(const float4*)(&rp[hw]);
                    v0 += r.x; v1 += r.y; v2 += r.z; v3 += r.w;
                }
                if constexpr (MODE != 0) {
                    v0 = fmaxf(v0, 0.f); v1 = fmaxf(v1, 0.f);
                    v2 = fmaxf(v2, 0.f); v3 = fmaxf(v3, 0.f);
                }
                *(float4*)(&op[hw]) = make_float4(v0, v1, v2, v3);
            }
        }
    }
}

// ---------------------------------------------------------------------------
// Heads: per-pixel 256-wide dots for obj / depth / offset(2).
// ---------------------------------------------------------------------------
__global__ __launch_bounds__(256)
void heads_kernel(const float* __restrict__ x,
                  const float* __restrict__ w_obj, const float* __restrict__ b_obj,
                  const float* __restrict__ w_dep, const float* __restrict__ b_dep,
                  const float* __restrict__ w_off, const float* __restrict__ b_off,
                  float* __restrict__ obj_out, float* __restrict__ depth_out,
                  float* __restrict__ off_out) {
    __shared__ float wo[256], wd[256], w0[256], w1[256];
    const int tid = threadIdx.x;
    wo[tid] = w_obj[tid];
    wd[tid] = w_dep[tid];
    w0[tid] = w_off[tid];
    w1[tid] = w_off[256 + tid];
    __syncthreads();

    const int g  = blockIdx.x * 256 + tid;   // 0..95999
    const int b  = g / HWN;
    const int hw = g - b * HWN;
    const float* xp = x + ((size_t)b * CH) * HWN + hw;

    float ao = 0.f, ad = 0.f, a0 = 0.f, a1 = 0.f;
#pragma unroll 8
    for (int c = 0; c < CH; ++c) {
        const float v = xp[(size_t)c * HWN];
        ao = fmaf(wo[c], v, ao);
        ad = fmaf(wd[c], v, ad);
        a0 = fmaf(w0[c], v, a0);
        a1 = fmaf(w1[c], v, a1);
    }
    const float zo = ao + b_obj[0];
    float so = 1.f / (1.f + expf(-zo));
    so = fminf(fmaxf(so, 1e-4f), 1.f - 1e-4f);
    obj_out[g] = so;

    const float zd = ad + b_dep[0];
    const float sd = 1.f / (1.f + expf(-zd));
    depth_out[g] = 1.f / sd - 1.f;

    off_out[(b * 2 + 0) * HWN + hw] = a0 + b_off[0];
    off_out[(b * 2 + 1) * HWN + hw] = a1 + b_off[1];
}

// ---------------------------------------------------------------------------
// Top-200 (exact, jax.lax.top_k tie semantics: value desc, index asc) via
// 3-pass radix select on float bits, then bitonic sort of candidates, then
// fused grid-sample + K^-1 projection epilogue.  One block per batch.
// ---------------------------------------------------------------------------
__global__ __launch_bounds__(256)
void topk_final_kernel(const float* __restrict__ obj,
                       const float* __restrict__ depth_map,
                       const float* __restrict__ off_map,
                       const float* __restrict__ Ks,
                       float* __restrict__ conf_out,
                       float* __restrict__ xyz_out) {
    const int b   = blockIdx.x;
    const int tid = threadIdx.x;
    const float* data = obj + b * HWN;

    __shared__ unsigned hist[2048];
    __shared__ unsigned partial[256];
    __shared__ unsigned sh_sel, sh_cum;
    __shared__ unsigned long long comp[1024];
    __shared__ unsigned ncand;

    unsigned prefix = 0;
    int r = PNUM;

    for (int lvl = 0; lvl < 3; ++lvl) {
        const int shift  = (lvl == 0) ? 21 : (lvl == 1) ? 10 : 0;
        const int bits   = (lvl == 2) ? 10 : 11;
        const int nb     = 1 << bits;
        const int pshift = shift + bits;

        for (int i = tid; i < 2048; i += 256) hist[i] = 0;
        __syncthreads();
        for (int i = tid; i < HWN; i += 256) {
            const unsigned k = __float_as_uint(data[i]);
            if (lvl == 0 || (k >> pshift) == prefix)
                atomicAdd(&hist[(k >> shift) & (nb - 1)], 1u);
        }
        __syncthreads();
        const int per = nb / 256;
        unsigned ps = 0;
        for (int j = 0; j < per; ++j) ps += hist[tid * per + j];
        partial[tid] = ps;
        __syncthreads();
        if (tid == 0) {
            unsigned cum = 0;
            int chunk = 0;
            for (int c = 255; c >= 0; --c) {
                if (cum + partial[c] >= (unsigned)r) { chunk = c; break; }
                cum += partial[c];
            }
            int selb = 0;
            for (int c2 = chunk * per + per - 1;; --c2) {
                if (cum + hist[c2] >= (unsigned)r) { selb = c2; break; }
                cum += hist[c2];
            }
            sh_sel = (unsigned)selb;
            sh_cum = cum;
        }
        __syncthreads();
        prefix = (prefix << bits) | sh_sel;
        r -= (int)sh_cum;
        __syncthreads();
    }
    const unsigned T = prefix;    // exact 200th-largest key

    if (tid == 0) ncand = 0;
    __syncthreads();
    for (int i = tid; i < HWN; i += 256) {
        const unsigned k = __float_as_uint(data[i]);
        if (k >= T) {
            const unsigned pos = atomicAdd(&ncand, 1u);
            if (pos < 1024)
                comp[pos] = ((unsigned long long)k << 32) | (unsigned)(~(unsigned)i);
        }
    }
    __syncthreads();
    const unsigned n = (ncand > 1024u) ? 1024u : ncand;
    for (int i = tid; i < 1024; i += 256)
        if ((unsigned)i >= n) comp[i] = 0ULL;
    __syncthreads();

    // bitonic sort, descending (key desc; ~idx desc == idx asc)
    for (int ksz = 2; ksz <= 1024; ksz <<= 1) {
        for (int jj = ksz >> 1; jj > 0; jj >>= 1) {
            __syncthreads();
            for (int e = tid; e < 1024; e += 256) {
                const int l = e ^ jj;
                if (l > e) {
                    const unsigned long long a = comp[e], c = comp[l];
                    const bool sw = ((e & ksz) == 0) ? (a < c) : (a > c);
                    if (sw) { comp[e] = c; comp[l] = a; }
                }
            }
        }
    }
    __syncthreads();

    if (tid < PNUM) {
        const unsigned long long c = comp[tid];
        const float conf = __uint_as_float((unsigned)(c >> 32));
        const int idx = (int)(~(unsigned)(c & 0xffffffffu));

        const float fu = (float)(idx % IMW);
        const float fv = (float)(idx / IMH);       // faithful: // feat_h (=120)
        const float nu = (fu - 100.f) / 100.f;
        const float nv = (fv - fv / 2.0f) / 60.f;  // faithful source expression

        const float xx = ((nu + 1.f) * 200.f - 1.f) * 0.5f;
        const float yy = ((nv + 1.f) * 120.f - 1.f) * 0.5f;
        const float x0f = floorf(xx), y0f = floorf(yy);
        const float wx1 = xx - x0f, wx0 = 1.f - wx1;
        const float wy1 = yy - y0f, wy0 = 1.f - wy1;

        const float* dm  = depth_map + b * HWN;
        const float* om0 = off_map + (b * 2) * HWN;
        const float* om1 = om0 + HWN;

        float d = 0.f, o0 = 0.f, o1 = 0.f;
#pragma unroll
        for (int cy = 0; cy < 2; ++cy) {
#pragma unroll
            for (int cx = 0; cx < 2; ++cx) {
                const float ix = x0f + (float)cx;
                const float iy = y0f + (float)cy;
                const float wgt = (cx ? wx1 : wx0) * (cy ? wy1 : wy0);
                const bool val = (ix >= 0.f) && (ix < 200.f) &&
                                 (iy >= 0.f) && (iy < 120.f);
                if (val) {
                    const int ixi = (int)ix;
                    const int iyi = (int)iy;
                    const int off = iyi * IMW + ixi;
                    d  = fmaf(dm[off],  wgt, d);
                    o0 = fmaf(om0[off], wgt, o0);
                    o1 = fmaf(om1[off], wgt, o1);
                }
            }
        }

        const float cu = (fu + o0) * 16.f;
        const float cv = (fv + o1) * 16.f;
        const float X = cu * d, Y = cv * d, Z = d;

        const float* K = Ks + b * 9;
        const float k0 = K[0], k1 = K[1], k2 = K[2];
        const float k3 = K[3], k4 = K[4], k5 = K[5];
        const float k6 = K[6], k7 = K[7], k8 = K[8];
        const float det = k0 * (k4 * k8 - k5 * k7)
                        - k1 * (k3 * k8 - k5 * k6)
                        + k2 * (k3 * k7 - k4 * k6);
        const float id_ = 1.f / det;
        const float i00 = (k4 * k8 - k5 * k7) * id_;
        const float i01 = (k2 * k7 - k1 * k8) * id_;
        const float i02 = (k1 * k5 - k2 * k4) * id_;
        const float i10 = (k5 * k6 - k3 * k8) * id_;
        const float i11 = (k0 * k8 - k2 * k6) * id_;
        const float i12 = (k2 * k3 - k0 * k5) * id_;
        const float i20 = (k3 * k7 - k4 * k6) * id_;
        const float i21 = (k1 * k6 - k0 * k7) * id_;
        const float i22 = (k0 * k4 - k1 * k3) * id_;

        conf_out[b * PNUM + tid] = conf;
        float* xp = xyz_out + (b * PNUM + tid) * 3;
        xp[0] = i00 * X + i01 * Y + i02 * Z;
        xp[1] = i10 * X + i11 * Y + i12 * Z;
        xp[2] = i20 * X + i21 * Y + i22 * Z;
    }
}

// ---------------------------------------------------------------------------
extern "C" void kernel_launch(void* const* d_in, const int* in_sizes, int n_in,
                              void* d_out, int out_size, void* d_ws, size_t ws_size,
                              hipStream_t stream) {
    const float* feat  = (const float*)d_in[0];
    const float* Ks    = (const float*)d_in[1];
    const float* w_sc  = (const float*)d_in[2];
    const float* b_sc  = (const float*)d_in[3];
    const float* w_bb1 = (const float*)d_in[4];
    const float* bn1s  = (const float*)d_in[5];
    const float* bn1b  = (const float*)d_in[6];
    const float* w_bb2 = (const float*)d_in[7];
    const float* bn2s  = (const float*)d_in[8];
    const float* bn2b  = (const float*)d_in[9];
    const float* w_obj = (const float*)d_in[10];
    const float* b_obj = (const float*)d_in[11];
    const float* w_dep = (const float*)d_in[12];
    const float* b_dep = (const float*)d_in[13];
    const float* w_off = (const float*)d_in[14];
    const float* b_off = (const float*)d_in[15];

    float* out = (float*)d_out;
    float* ws  = (float*)d_ws;

    float* x0    = ws + X0_OFF;
    float* h1    = ws + H1_OFF;
    float* xx    = ws + XX_OFF;
    float* depth = ws + DEP_OFF;
    float* offm  = ws + OFM_OFF;
    float* A0    = ws + A0_OFF;
    float* A1    = ws + A1_OFF;
    float* A2    = ws + A2_OFF;

    reorder_w_kernel<<<256, 256, 0, stream>>>(w_sc, A0, 1);
    reorder_w_kernel<<<2304, 256, 0, stream>>>(w_bb1, A1, 9);
    reorder_w_kernel<<<2304, 256, 0, stream>>>(w_bb2, A2, 9);

    dim3 cgrid(PPB * NBATCH, 2);
    conv_gemm_kernel<1, 0><<<cgrid, 256, 0, stream>>>(feat, A0, b_sc, nullptr, nullptr, x0);
    conv_gemm_kernel<9, 1><<<cgrid, 256, 0, stream>>>(x0, A1, bn1s, bn1b, nullptr, h1);
    conv_gemm_kernel<9, 2><<<cgrid, 256, 0, stream>>>(h1, A2, bn2s, bn2b, x0, xx);

    heads_kernel<<<375, 256, 0, stream>>>(xx, w_obj, b_obj, w_dep, b_dep,
                                          w_off, b_off, out, depth, offm);

    topk_final_kernel<<<NBATCH, 256, 0, stream>>>(out, depth, offm, Ks,
                                                  out + NBATCH * HWN,
                                                  out + NBATCH * HWN + NBATCH * PNUM);
}

// Round 5
// 3535.275 us; speedup vs baseline: 10.0627x; 4.2253x over previous
//
#include <hip/hip_runtime.h>
#include <cmath>

#define CH   256
#define IMH  120
#define IMW  200
#define HWN  24000        // 120*200
#define NBATCH 4
#define PPB  188          // ceil(24000/128) pixel tiles per batch
#define PNUM 200
#define NJOBS (NBATCH * PPB * 2)   // 1504 tile-jobs (b, px-tile, oc-half)
#define PGRID 512                  // persistent blocks: 2 blocks/CU x 256 CU

// workspace layout (float offsets). Total = 75,261,184 floats = ~301 MB.
#define X0_OFF   0
#define H1_OFF   24576000
#define XX_OFF   49152000
#define DEP_OFF  73728000
#define OFM_OFF  73824000
#define A0_OFF   74016000
#define A1_OFF   74081536
#define A2_OFF   74671360

// ---------------------------------------------------------------------------
// Weight reorder: src [oc][ic][taps] -> dst [tap][ic][oc]
// ---------------------------------------------------------------------------
__global__ void reorder_w_kernel(const float* __restrict__ src,
                                 float* __restrict__ dst, int taps) {
    int e = blockIdx.x * 256 + threadIdx.x;
    int total = CH * CH * taps;
    if (e >= total) return;
    int oc  = e / (CH * taps);
    int rem = e - oc * (CH * taps);
    int ic  = rem / taps;
    int t   = rem - ic * taps;
    dst[(t * CH + ic) * CH + oc] = src[e];
}

// ---------------------------------------------------------------------------
// Implicit-GEMM conv.  out[oc][px] = sum_{t,ic} A[t][ic][oc] * in[ic][h+dy][w+dx]
// MODE 0: out = acc + p0[oc]                      (conv1x1 + bias)
// MODE 1: out = relu(acc*p0[oc] + p1[oc])         (conv3x3 + BN + relu)
// MODE 2: out = relu(acc*p0[oc] + p1[oc] + resid) (conv3x3 + BN + residual + relu)
// Tile-job: 128 oc x 128 px, BK=8, 256 threads, 8x8 micro-tile, double-buffered
// LDS (16 KB), one barrier per K-step, loads issued before compute (T14).
// __launch_bounds__(256,2): 256-VGPR cap. Peak demand ~220 (64 acc + up to
// 128 hoisted LDS floats + staging). (256,3)'s 170 cap SPILLED (R4: 21 GB
// scratch writes); (256,4)'s 128 cap spilled worse (R3: 55 GB).
// Persistent blocks (512 = 2/CU): loop over 1504 jobs, 98% round efficiency.
// ---------------------------------------------------------------------------
template <int TAPS, int MODE>
__global__ __launch_bounds__(256, 2)
void conv_gemm_kernel(const float* __restrict__ in, const float* __restrict__ Aw,
                      const float* __restrict__ p0, const float* __restrict__ p1,
                      const float* __restrict__ resid, float* __restrict__ out) {
    const int tid = threadIdx.x;
    const int ti  = tid >> 4;      // 0..15 -> oc group of 8
    const int tj  = tid & 15;      // 0..15 -> px group of 4 (+64)

    __shared__ float As[2][8][128];
    __shared__ float Bs[2][8][128];

    // staging assignment: thread stages one float4 of A and 4 elems of B
    const int sk = tid >> 5;         // 0..7 (k row)
    const int sc = (tid & 31) * 4;   // col (oc or px), multiple of 4

    const int NS = TAPS * 32;     // K-steps of 8

#pragma unroll 1
    for (int job = blockIdx.x; job < NJOBS; job += PGRID) {
        const int ocH = job & 1;
        const int tt  = job >> 1;
        const int b   = tt / PPB;
        const int hw0 = (tt - b * PPB) * 128;
        const int oc0 = ocH * 128;

        float acc[8][8];
#pragma unroll
        for (int i = 0; i < 8; ++i)
#pragma unroll
            for (int j = 0; j < 8; ++j) acc[i][j] = 0.f;

        // B pixel geometry for the 4 staged elements (computed once per job)
        int ph[4], pw[4];
        bool pv[4];
        {
            const int px0 = hw0 + sc;
            int phh = px0 / IMW;
            int pww = px0 - phh * IMW;
#pragma unroll
            for (int e = 0; e < 4; ++e) {
                ph[e] = phh; pw[e] = pww;
                pv[e] = (px0 + e) < HWN;
                if (++pww == IMW) { pww = 0; ++phh; }
            }
        }

        const float* inb = in + (size_t)b * (CH * HWN);

        float4 aA;
        float  vB[4];
        bool   okB[4];

#define ISSUE(sNext)                                                        \
    {                                                                       \
        const int tap_ = (TAPS == 9) ? ((sNext) >> 5) : 0;                  \
        const int kc_  = (sNext) & 31;                                      \
        const int ic_  = kc_ * 8 + sk;                                      \
        const int dy_  = (TAPS == 9) ? (tap_ / 3 - 1) : 0;                  \
        const int dx_  = (TAPS == 9) ? (tap_ - (tap_ / 3) * 3 - 1) : 0;     \
        aA = *(const float4*)(Aw + ((tap_ * CH + ic_) * CH + oc0 + sc));    \
        _Pragma("unroll")                                                   \
        for (int e = 0; e < 4; ++e) {                                       \
            const int hh_ = ph[e] + dy_, ww_ = pw[e] + dx_;                 \
            okB[e] = pv[e] && ((unsigned)hh_ < IMH) && ((unsigned)ww_ < IMW);\
            const int off_ = okB[e] ? (ic_ * HWN + hh_ * IMW + ww_) : 0;    \
            vB[e] = inb[off_];                                              \
        }                                                                   \
    }

#define COMMIT(buf)                                                         \
    {                                                                       \
        float4 bv;                                                          \
        bv.x = okB[0] ? vB[0] : 0.f;                                        \
        bv.y = okB[1] ? vB[1] : 0.f;                                        \
        bv.z = okB[2] ? vB[2] : 0.f;                                        \
        bv.w = okB[3] ? vB[3] : 0.f;                                        \
        *(float4*)(&As[buf][sk][sc]) = aA;                                  \
        *(float4*)(&Bs[buf][sk][sc]) = bv;                                  \
    }

        // prologue: stage tile 0 into buffer 0
        ISSUE(0);
        COMMIT(0);
        __syncthreads();

        int cur = 0;
#pragma unroll 1
        for (int s = 0; s < NS; ++s) {
            if (s + 1 < NS) ISSUE(s + 1);

#pragma unroll
            for (int k = 0; k < 8; ++k) {
                const float4 a0 = *(const float4*)(&As[cur][k][ti * 8]);
                const float4 a1 = *(const float4*)(&As[cur][k][ti * 8 + 4]);
                const float4 b0 = *(const float4*)(&Bs[cur][k][tj * 4]);
                const float4 b1 = *(const float4*)(&Bs[cur][k][64 + tj * 4]);
                const float av[8] = {a0.x, a0.y, a0.z, a0.w, a1.x, a1.y, a1.z, a1.w};
                const float bv[8] = {b0.x, b0.y, b0.z, b0.w, b1.x, b1.y, b1.z, b1.w};
#pragma unroll
                for (int i = 0; i < 8; ++i)
#pragma unroll
                    for (int j = 0; j < 8; ++j)
                        acc[i][j] = fmaf(av[i], bv[j], acc[i][j]);
            }

            if (s + 1 < NS) COMMIT(cur ^ 1);
            __syncthreads();
            cur ^= 1;
        }
#undef ISSUE
#undef COMMIT

        // epilogue (register-only; LDS may be re-staged by next job safely)
        const int ocb = oc0 + ti * 8;
#pragma unroll
        for (int i = 0; i < 8; ++i) {
            const int oc = ocb + i;
            float sS, bi;
            if constexpr (MODE == 0) { sS = 1.f; bi = p0[oc]; }
            else                     { sS = p0[oc]; bi = p1[oc]; }
            float* op = out + ((size_t)b * CH + oc) * HWN;
            const float* rp = (MODE == 2) ? (resid + ((size_t)b * CH + oc) * HWN) : nullptr;
#pragma unroll
            for (int g = 0; g < 2; ++g) {
                const int hw = hw0 + g * 64 + tj * 4;
                if (hw < HWN) {
                    float v0 = acc[i][g * 4 + 0] * sS + bi;
                    float v1 = acc[i][g * 4 + 1] * sS + bi;
                    float v2 = acc[i][g * 4 + 2] * sS + bi;
                    float v3 = acc[i][g * 4 + 3] * sS + bi;
                    if constexpr (MODE == 2) {
                        const float4 r = *(const float4*)(&rp[hw]);
                        v0 += r.x; v1 += r.y; v2 += r.z; v3 += r.w;
                    }
                    if constexpr (MODE != 0) {
                        v0 = fmaxf(v0, 0.f); v1 = fmaxf(v1, 0.f);
                        v2 = fmaxf(v2, 0.f); v3 = fmaxf(v3, 0.f);
                    }
                    *(float4*)(&op[hw]) = make_float4(v0, v1, v2, v3);
                }
            }
        }
    }
}

// ---------------------------------------------------------------------------
// Heads: per-pixel 256-wide dots for obj / depth / offset(2).
// ---------------------------------------------------------------------------
__global__ __launch_bounds__(256)
void heads_kernel(const float* __restrict__ x,
                  const float* __restrict__ w_obj, const float* __restrict__ b_obj,
                  const float* __restrict__ w_dep, const float* __restrict__ b_dep,
                  const float* __restrict__ w_off, const float* __restrict__ b_off,
                  float* __restrict__ obj_out, float* __restrict__ depth_out,
                  float* __restrict__ off_out) {
    __shared__ float wo[256], wd[256], w0[256], w1[256];
    const int tid = threadIdx.x;
    wo[tid] = w_obj[tid];
    wd[tid] = w_dep[tid];
    w0[tid] = w_off[tid];
    w1[tid] = w_off[256 + tid];
    __syncthreads();

    const int g  = blockIdx.x * 256 + tid;   // 0..95999
    const int b  = g / HWN;
    const int hw = g - b * HWN;
    const float* xp = x + ((size_t)b * CH) * HWN + hw;

    float ao = 0.f, ad = 0.f, a0 = 0.f, a1 = 0.f;
#pragma unroll 8
    for (int c = 0; c < CH; ++c) {
        const float v = xp[(size_t)c * HWN];
        ao = fmaf(wo[c], v, ao);
        ad = fmaf(wd[c], v, ad);
        a0 = fmaf(w0[c], v, a0);
        a1 = fmaf(w1[c], v, a1);
    }
    const float zo = ao + b_obj[0];
    float so = 1.f / (1.f + expf(-zo));
    so = fminf(fmaxf(so, 1e-4f), 1.f - 1e-4f);
    obj_out[g] = so;

    const float zd = ad + b_dep[0];
    const float sd = 1.f / (1.f + expf(-zd));
    depth_out[g] = 1.f / sd - 1.f;

    off_out[(b * 2 + 0) * HWN + hw] = a0 + b_off[0];
    off_out[(b * 2 + 1) * HWN + hw] = a1 + b_off[1];
}

// ---------------------------------------------------------------------------
// Top-200 (exact, jax.lax.top_k tie semantics: value desc, index asc) via
// 3-pass radix select on float bits, then bitonic sort of candidates, then
// fused grid-sample + K^-1 projection epilogue.  One block per batch.
// ---------------------------------------------------------------------------
__global__ __launch_bounds__(256)
void topk_final_kernel(const float* __restrict__ obj,
                       const float* __restrict__ depth_map,
                       const float* __restrict__ off_map,
                       const float* __restrict__ Ks,
                       float* __restrict__ conf_out,
                       float* __restrict__ xyz_out) {
    const int b   = blockIdx.x;
    const int tid = threadIdx.x;
    const float* data = obj + b * HWN;

    __shared__ unsigned hist[2048];
    __shared__ unsigned partial[256];
    __shared__ unsigned sh_sel, sh_cum;
    __shared__ unsigned long long comp[1024];
    __shared__ unsigned ncand;

    unsigned prefix = 0;
    int r = PNUM;

    for (int lvl = 0; lvl < 3; ++lvl) {
        const int shift  = (lvl == 0) ? 21 : (lvl == 1) ? 10 : 0;
        const int bits   = (lvl == 2) ? 10 : 11;
        const int nb     = 1 << bits;
        const int pshift = shift + bits;

        for (int i = tid; i < 2048; i += 256) hist[i] = 0;
        __syncthreads();
        for (int i = tid; i < HWN; i += 256) {
            const unsigned k = __float_as_uint(data[i]);
            if (lvl == 0 || (k >> pshift) == prefix)
                atomicAdd(&hist[(k >> shift) & (nb - 1)], 1u);
        }
        __syncthreads();
        const int per = nb / 256;
        unsigned ps = 0;
        for (int j = 0; j < per; ++j) ps += hist[tid * per + j];
        partial[tid] = ps;
        __syncthreads();
        if (tid == 0) {
            unsigned cum = 0;
            int chunk = 0;
            for (int c = 255; c >= 0; --c) {
                if (cum + partial[c] >= (unsigned)r) { chunk = c; break; }
                cum += partial[c];
            }
            int selb = 0;
            for (int c2 = chunk * per + per - 1;; --c2) {
                if (cum + hist[c2] >= (unsigned)r) { selb = c2; break; }
                cum += hist[c2];
            }
            sh_sel = (unsigned)selb;
            sh_cum = cum;
        }
        __syncthreads();
        prefix = (prefix << bits) | sh_sel;
        r -= (int)sh_cum;
        __syncthreads();
    }
    const unsigned T = prefix;    // exact 200th-largest key

    if (tid == 0) ncand = 0;
    __syncthreads();
    for (int i = tid; i < HWN; i += 256) {
        const unsigned k = __float_as_uint(data[i]);
        if (k >= T) {
            const unsigned pos = atomicAdd(&ncand, 1u);
            if (pos < 1024)
                comp[pos] = ((unsigned long long)k << 32) | (unsigned)(~(unsigned)i);
        }
    }
    __syncthreads();
    const unsigned n = (ncand > 1024u) ? 1024u : ncand;
    for (int i = tid; i < 1024; i += 256)
        if ((unsigned)i >= n) comp[i] = 0ULL;
    __syncthreads();

    // bitonic sort, descending (key desc; ~idx desc == idx asc)
    for (int ksz = 2; ksz <= 1024; ksz <<= 1) {
        for (int jj = ksz >> 1; jj > 0; jj >>= 1) {
            __syncthreads();
            for (int e = tid; e < 1024; e += 256) {
                const int l = e ^ jj;
                if (l > e) {
                    const unsigned long long a = comp[e], c = comp[l];
                    const bool sw = ((e & ksz) == 0) ? (a < c) : (a > c);
                    if (sw) { comp[e] = c; comp[l] = a; }
                }
            }
        }
    }
    __syncthreads();

    if (tid < PNUM) {
        const unsigned long long c = comp[tid];
        const float conf = __uint_as_float((unsigned)(c >> 32));
        const int idx = (int)(~(unsigned)(c & 0xffffffffu));

        const float fu = (float)(idx % IMW);
        const float fv = (float)(idx / IMH);       // faithful: // feat_h (=120)
        const float nu = (fu - 100.f) / 100.f;
        const float nv = (fv - fv / 2.0f) / 60.f;  // faithful source expression

        const float xx = ((nu + 1.f) * 200.f - 1.f) * 0.5f;
        const float yy = ((nv + 1.f) * 120.f - 1.f) * 0.5f;
        const float x0f = floorf(xx), y0f = floorf(yy);
        const float wx1 = xx - x0f, wx0 = 1.f - wx1;
        const float wy1 = yy - y0f, wy0 = 1.f - wy1;

        const float* dm  = depth_map + b * HWN;
        const float* om0 = off_map + (b * 2) * HWN;
        const float* om1 = om0 + HWN;

        float d = 0.f, o0 = 0.f, o1 = 0.f;
#pragma unroll
        for (int cy = 0; cy < 2; ++cy) {
#pragma unroll
            for (int cx = 0; cx < 2; ++cx) {
                const float ix = x0f + (float)cx;
                const float iy = y0f + (float)cy;
                const float wgt = (cx ? wx1 : wx0) * (cy ? wy1 : wy0);
                const bool val = (ix >= 0.f) && (ix < 200.f) &&
                                 (iy >= 0.f) && (iy < 120.f);
                if (val) {
                    const int ixi = (int)ix;
                    const int iyi = (int)iy;
                    const int off = iyi * IMW + ixi;
                    d  = fmaf(dm[off],  wgt, d);
                    o0 = fmaf(om0[off], wgt, o0);
                    o1 = fmaf(om1[off], wgt, o1);
                }
            }
        }

        const float cu = (fu + o0) * 16.f;
        const float cv = (fv + o1) * 16.f;
        const float X = cu * d, Y = cv * d, Z = d;

        const float* K = Ks + b * 9;
        const float k0 = K[0], k1 = K[1], k2 = K[2];
        const float k3 = K[3], k4 = K[4], k5 = K[5];
        const float k6 = K[6], k7 = K[7], k8 = K[8];
        const float det = k0 * (k4 * k8 - k5 * k7)
                        - k1 * (k3 * k8 - k5 * k6)
                        + k2 * (k3 * k7 - k4 * k6);
        const float id_ = 1.f / det;
        const float i00 = (k4 * k8 - k5 * k7) * id_;
        const float i01 = (k2 * k7 - k1 * k8) * id_;
        const float i02 = (k1 * k5 - k2 * k4) * id_;
        const float i10 = (k5 * k6 - k3 * k8) * id_;
        const float i11 = (k0 * k8 - k2 * k6) * id_;
        const float i12 = (k2 * k3 - k0 * k5) * id_;
        const float i20 = (k3 * k7 - k4 * k6) * id_;
        const float i21 = (k1 * k6 - k0 * k7) * id_;
        const float i22 = (k0 * k4 - k1 * k3) * id_;

        conf_out[b * PNUM + tid] = conf;
        float* xp = xyz_out + (b * PNUM + tid) * 3;
        xp[0] = i00 * X + i01 * Y + i02 * Z;
        xp[1] = i10 * X + i11 * Y + i12 * Z;
        xp[2] = i20 * X + i21 * Y + i22 * Z;
    }
}

// ---------------------------------------------------------------------------
extern "C" void kernel_launch(void* const* d_in, const int* in_sizes, int n_in,
                              void* d_out, int out_size, void* d_ws, size_t ws_size,
                              hipStream_t stream) {
    const float* feat  = (const float*)d_in[0];
    const float* Ks    = (const float*)d_in[1];
    const float* w_sc  = (const float*)d_in[2];
    const float* b_sc  = (const float*)d_in[3];
    const float* w_bb1 = (const float*)d_in[4];
    const float* bn1s  = (const float*)d_in[5];
    const float* bn1b  = (const float*)d_in[6];
    const float* w_bb2 = (const float*)d_in[7];
    const float* bn2s  = (const float*)d_in[8];
    const float* bn2b  = (const float*)d_in[9];
    const float* w_obj = (const float*)d_in[10];
    const float* b_obj = (const float*)d_in[11];
    const float* w_dep = (const float*)d_in[12];
    const float* b_dep = (const float*)d_in[13];
    const float* w_off = (const float*)d_in[14];
    const float* b_off = (const float*)d_in[15];

    float* out = (float*)d_out;
    float* ws  = (float*)d_ws;

    float* x0    = ws + X0_OFF;
    float* h1    = ws + H1_OFF;
    float* xx    = ws + XX_OFF;
    float* depth = ws + DEP_OFF;
    float* offm  = ws + OFM_OFF;
    float* A0    = ws + A0_OFF;
    float* A1    = ws + A1_OFF;
    float* A2    = ws + A2_OFF;

    reorder_w_kernel<<<256, 256, 0, stream>>>(w_sc, A0, 1);
    reorder_w_kernel<<<2304, 256, 0, stream>>>(w_bb1, A1, 9);
    reorder_w_kernel<<<2304, 256, 0, stream>>>(w_bb2, A2, 9);

    conv_gemm_kernel<1, 0><<<PGRID, 256, 0, stream>>>(feat, A0, b_sc, nullptr, nullptr, x0);
    conv_gemm_kernel<9, 1><<<PGRID, 256, 0, stream>>>(x0, A1, bn1s, bn1b, nullptr, h1);
    conv_gemm_kernel<9, 2><<<PGRID, 256, 0, stream>>>(h1, A2, bn2s, bn2b, x0, xx);

    heads_kernel<<<375, 256, 0, stream>>>(xx, w_obj, b_obj, w_dep, b_dep,
                                          w_off, b_off, out, depth, offm);

    topk_final_kernel<<<NBATCH, 256, 0, stream>>>(out, depth, offm, Ks,
                                                  out + NBATCH * HWN,
                                                  out + NBATCH * HWN + NBATCH * PNUM);
}